// Round 18
// baseline (154.048 us; speedup 1.0000x reference)
//
#include <hip/hip_runtime.h>

typedef unsigned int uint;
typedef unsigned short ushort;
typedef short bf16x8 __attribute__((ext_vector_type(8)));
typedef _Float16 f16x8 __attribute__((ext_vector_type(8)));
typedef float f32x4 __attribute__((ext_vector_type(4)));

#define NEG_SLOPE 0.2f

// ---------------- workspace layout (bytes) ----------------
#define WS_HIST 0                       // 4*4096*4 = 65536
#define WS_DBL  65536                   // 88 doubles
#define WS_BLV  (WS_DBL + 704)         // 60 floats
#define WS_WA   (WS_BLV + 256)        // 16x128 bf16 = 4096 B
#define WS_W2A  (WS_WA + 4096)        // 5tf x 5step x 64lane x 8 f16 = 25600 B
#define WS_ZERO_BYTES (WS_DBL + 704)

// h2 LDS geometry: [2 bufs][18 rows][18 cols][24 ch-stride]
#define HCH 24
#define HROW 432      // 18*24
#define HBUF 7776     // 324*24

__device__ __forceinline__ float leakyf(float x) { return fmaxf(x, NEG_SLOPE * x); }

__device__ __forceinline__ ushort f2bf(float f) {
  uint u = __float_as_uint(f);
  uint r = u + 0x7FFFu + ((u >> 16) & 1u);
  return (ushort)(r >> 16);
}
// pack 2 f32 -> 2 f16 in one dword (v_cvt_pkrtz_f16_f32)
__device__ __forceinline__ uint cvt_pk_u32(float a, float b) {
  union { __fp16 __attribute__((ext_vector_type(2))) h; uint u; } c;
  c.h = __builtin_amdgcn_cvt_pkrtz(a, b);
  return c.u;
}
// pack 2 f32 -> 2 bf16 in one dword (v_cvt_pk_bf16_f32, no builtin on gfx950)
__device__ __forceinline__ uint cvt_pk_bf16(float a, float b) {
  uint r;
  asm("v_cvt_pk_bf16_f32 %0, %1, %2" : "=v"(r) : "v"(a), "v"(b));
  return r;
}

// ---------------- fused stats: i-plane sums + center G/B stats + median hist + j sums ----------------
__global__ __launch_bounds__(256) void stats_kernel(const float* __restrict__ gi,
                                                    const float* __restrict__ gj,
                                                    double* __restrict__ sums,
                                                    uint* __restrict__ hist) {
  __shared__ double red[256];
  __shared__ uint lh[4096];
  const int plane = blockIdx.y;          // 0..59 = i planes, 60..71 = j planes
  const int chunk = blockIdx.x;          // 0..31
  const int tid = threadIdx.x;

  if (plane >= 60) {
    const int jp = plane - 60;
    const float4* base = (const float4*)(gj + (size_t)jp * 262144);
    double dsum = 0.0;
    for (int k = 0; k < 8; ++k) {
      float4 v = base[chunk * 2048 + k * 256 + tid];
      dsum += (double)v.x + (double)v.y + (double)v.z + (double)v.w;
    }
    red[tid] = dsum; __syncthreads();
    for (int off = 128; off > 0; off >>= 1) { if (tid < off) red[tid] += red[tid + off]; __syncthreads(); }
    if (tid == 0) atomicAdd(&sums[60 + jp], red[0]);
    return;
  }

  const int b = plane / 15;
  const int rem = plane % 15;
  const int c = rem / 5;
  const int t = rem % 5;
  const float4* base = (const float4*)(gi + (size_t)plane * 262144);
  const bool dostat = (c >= 1 && t == 2);
  const bool domed = (c == 0 && t == 2);
  if (domed) {
    for (int i = tid; i < 4096; i += 256) lh[i] = 0;
    __syncthreads();
  }
  double dsum = 0.0, dsx = 0.0, dsx2 = 0.0;
  for (int k = 0; k < 8; ++k) {
    float4 v = base[chunk * 2048 + k * 256 + tid];
    dsum += (double)v.x + (double)v.y + (double)v.z + (double)v.w;
    if (dostat || domed) {
      float arr[4] = {v.x, v.y, v.z, v.w};
#pragma unroll
      for (int q = 0; q < 4; ++q) {
        float x = fminf(fmaxf(arr[q], 0.f), 1.f) * 255.f;
        if (domed) {
          int bin = (int)(x * (4096.0f / 255.0f));
          if (bin > 4095) bin = 4095;
          atomicAdd(&lh[bin], 1u);
        } else {
          dsx += (double)x;
          dsx2 += (double)x * (double)x;
        }
      }
    }
  }
  red[tid] = dsum; __syncthreads();
  for (int off = 128; off > 0; off >>= 1) { if (tid < off) red[tid] += red[tid + off]; __syncthreads(); }
  if (tid == 0) atomicAdd(&sums[plane], red[0]);
  __syncthreads();
  if (dostat) {
    red[tid] = dsx; __syncthreads();
    for (int off = 128; off > 0; off >>= 1) { if (tid < off) red[tid] += red[tid + off]; __syncthreads(); }
    if (tid == 0) atomicAdd(&sums[72 + b * 2 + (c - 1)], red[0]);
    __syncthreads();
    red[tid] = dsx2; __syncthreads();
    for (int off = 128; off > 0; off >>= 1) { if (tid < off) red[tid] += red[tid + off]; __syncthreads(); }
    if (tid == 0) atomicAdd(&sums[80 + b * 2 + (c - 1)], red[0]);
  }
  if (domed) {
    for (int i = tid; i < 4096; i += 256) { uint v = lh[i]; if (v) atomicAdd(&hist[b * 4096 + i], v); }
  }
}

// ---------------- weight prep: bf16 conv1 A (16x128) + f16 conv2 A-table ----------------
__global__ void setup_kernel(const float* __restrict__ w_t1, const float* __restrict__ w_t2,
                             ushort* __restrict__ wA, ushort* __restrict__ w2A) {
  const int tid = threadIdx.x;
  for (int idx = tid; idx < 2048; idx += 256) {
    int o = idx >> 7, k = idx & 127, g = k >> 2, kw = k & 3;
    float v = 0.f;
    if (g < 27 && kw < 3) {
      int ci = g / 9, kd = (g % 9) / 3, kh = g % 3;
      v = w_t1[o * 81 + ci * 27 + kd * 9 + kh * 3 + kw];
    }
    wA[idx] = f2bf(v);
  }
  for (int idx = tid; idx < 12800; idx += 256) {
    int j = idx & 7;
    int lane = (idx >> 3) & 63;
    int rest = idx >> 9;            // 0..24
    int step = rest % 5;
    int tf = rest / 5;
    int ln = lane & 15, kb = lane >> 4;
    int k = kb * 8 + j;
    int tap = step * 2 + (k >> 4);
    int ch = k & 15;
    float v = 0.f;
    if (ln < 5 && tap < 9) {
      int kd = tf + 1 - ln;
      if (kd >= 0 && kd <= 2) v = w_t2[ch * 27 + kd * 9 + tap];
    }
    union { ushort s; _Float16 h; } cv; cv.h = (_Float16)v;
    w2A[idx] = cv.s;
  }
}

// ---------------- finalize: median scan + stats -> MLP -> blv ----------------
__global__ __launch_bounds__(256) void finalize_kernel(const uint* __restrict__ hist,
                                const double* __restrict__ sums,
                                const float* __restrict__ w_bl1, const float* __restrict__ b_bl1,
                                const float* __restrict__ w_bl2, const float* __restrict__ b_bl2,
                                const float* __restrict__ w1, float* __restrict__ blv) {
  __shared__ uint s[256];
  __shared__ float fv[2];
  __shared__ float rmed_s[4];
  const int tid = threadIdx.x;
  for (int b = 0; b < 4; ++b) {
    const uint* h = hist + b * 4096;
    uint loc[16]; uint part = 0;
#pragma unroll
    for (int q = 0; q < 16; ++q) { loc[q] = h[tid * 16 + q]; part += loc[q]; }
    s[tid] = part; __syncthreads();
    for (int off = 1; off < 256; off <<= 1) {
      uint v = (tid >= off) ? s[tid - off] : 0u;
      __syncthreads(); s[tid] += v; __syncthreads();
    }
    uint pref = s[tid] - part;
#pragma unroll
    for (int m = 0; m < 2; ++m) {
      uint k = 131071u + (uint)m;
      if (k >= pref && k < pref + part) {
        uint cum = pref;
        for (int q = 0; q < 16; ++q) {
          if (k < cum + loc[q]) { fv[m] = ((float)(tid * 16 + q) + 0.5f) * (255.f / 4096.f); break; }
          cum += loc[q];
        }
      }
    }
    __syncthreads();
    if (tid == 0) rmed_s[b] = 0.5f * (fv[0] + fv[1]);
    __syncthreads();
  }
  if (tid < 20) {
    const int b = tid / 5, t = tid % 5;
    const double inv = 1.0 / 262144.0;
    float bl2[3];
    bl2[0] = 140.f / (1.f + 14.4f * expf(-0.034f * rmed_s[b]));
    for (int c = 1; c < 3; ++c) {
      double m = sums[72 + b * 2 + (c - 1)] * inv;
      double ex2 = sums[80 + b * 2 + (c - 1)] * inv;
      double var = ex2 - m * m;
      if (var < 0.0) var = 0.0;
      bl2[c] = (float)(1.13 * m + 1.11 * sqrt(var) - 25.6);
    }
#pragma unroll
    for (int c = 0; c < 3; ++c)
      bl2[c] = fminf(fmaxf(bl2[c], 5.f), 250.f) * (1.f / 255.f);
    float diff[3];
    for (int c = 0; c < 3; ++c)
      diff[c] = (float)((sums[(b * 3 + c) * 5 + t] - sums[60 + b * 3 + c]) * inv);
    float h1[16];
    for (int o = 0; o < 16; ++o) {
      float sv = b_bl1[o];
      for (int c = 0; c < 3; ++c) sv += w_bl1[o * 3 + c] * diff[c];
      h1[o] = leakyf(sv);
    }
    const float w1v = w1[0];
    for (int c = 0; c < 3; ++c) {
      float sv = b_bl2[c];
      for (int o = 0; o < 16; ++o) sv += w_bl2[c * 16 + o] * h1[o];
      float sg = 1.f / (1.f + expf(-sv));
      blv[(b * 3 + c) * 5 + t] = bl2[c] + w1v * sg;
    }
  }
}

// ---------------- fused: 1 barrier/frame; pair staging; conv2 s-outer (1 aw live) ----------------
// Register-slimmed to fit the 4-block/CU cap (128 effective regs): aw[5] array removed.
__global__ __launch_bounds__(256, 4) void fused_kernel(
    const float* __restrict__ gi, const float* __restrict__ gj,
    const ushort* __restrict__ wAg, const float* __restrict__ b_t1,
    const ushort* __restrict__ w2Ag, const float* __restrict__ b_t2,
    const float* __restrict__ w2p, const float* __restrict__ t_bias,
    const float* __restrict__ blv, float* __restrict__ out) {
  __shared__ __align__(16) ushort xsh[10560];      // 2 parity copies x 4 slots x [3][20][22] bf16
  __shared__ __align__(16) ushort h2sh[2 * HBUF];  // h2 f16 double-buffered [2][18][18][24]
  __shared__ __align__(16) int baseTab[160];       // [tf][kb][e] conv1 slot bases
  __shared__ float blv_s[15];

  const int b = blockIdx.z;
  const int lin = blockIdx.y * 32 + blockIdx.x;
  const int swz = (lin & 7) * 128 + (lin >> 3);
  const int tY = swz >> 5, tX = swz & 31;
  const int tid = threadIdx.x;
  const int wv = tid >> 6;
  const int lane = tid & 63;
  const int ln = lane & 15;
  const int kb = lane >> 4;
  const int ty = tid >> 4, tx = tid & 15;
  const int gy = tY * 16 + ty, gx = tX * 16 + tx;
  const int ybase = tY * 16 - 2, xbase = tX * 16 - 2;

  if (tid < 15) blv_s[tid] = blv[b * 15 + tid];
  for (int i = tid; i < 5280; i += 256) ((uint*)xsh)[i] = 0u;
  // baseTab[tf][kb][e]: f=tf+kd-1: f<0 -> slot3 (zero at phase0), f>4 -> slot1 (zero-filled at
  // phase3), valid -> slot f%4; pad groups -> slot3 (finite data, zero A-weight).
  if (tid < 160) {
    int tf_ = tid >> 5, kb_ = (tid >> 3) & 3, e = tid & 7;
    int g = (e >> 1) * 8 + kb_ * 2 + (e & 1);
    int sl = 3, sb = 0;
    if (g < 27) {
      int ci = g / 9, r9 = g % 9, kd = r9 / 3, kh = r9 % 3;
      sb = ci * 440 + kh * 22;
      int f = tf_ + kd - 1;
      sl = (f < 0) ? 3 : (f > 4) ? 1 : (f & 3);
    }
    baseTab[tid] = sb + sl * 1320;
  }

  // conv1 A fragments + bias
  union { uint4 u; bf16x8 v; } a4[4];
#pragma unroll
  for (int m = 0; m < 4; ++m)
    a4[m].u = *(const uint4*)(wAg + ln * 128 + m * 32 + kb * 8);
  f32x4 bias4;
#pragma unroll
  for (int r = 0; r < 4; ++r) bias4[r] = b_t1[kb * 4 + r];

  // conv1 per-tile statics (tile = wv + i*4): pT = q | (pe<<13)
  int pT[6];
  uint tmask = 0;   // bit i: pos<324 (store valid); bit i+8: inimg
#pragma unroll
  for (int i = 0; i < 6; ++i) {
    int tile = wv + i * 4;
    int pos = tile * 16 + ln;
    int pe = pos < 324 ? pos : 323;
    int y0 = pe / 18, x0 = pe - y0 * 18;
    int p = x0 & 1;
    pT[i] = (y0 * 22 + x0 - p + p * 5280) | (pe << 13);
    int gyh = tY * 16 - 1 + y0, gxh = tX * 16 - 1 + x0;
    if (pos < 324) tmask |= 1u << i;
    if (gyh >= 0 && gyh < 512 && gxh >= 0 && gxh < 512) tmask |= 1u << (i + 8);
  }

  // conv2 per-lane B offsets (elem units; every term mult of 8 elems = 16 B -> b128-aligned)
  int bOff[5];
#pragma unroll
  for (int s = 0; s < 5; ++s) {
    int tap = s * 2 + (kb >> 1); if (tap > 8) tap = 8;
    int kh = tap / 3, kw = tap - kh * 3;
    bOff[s] = kh * HROW + kw * HCH + (kb & 1) * 8 + ln * HCH;
  }

  // staging precompute: PAIRS. p = tid + k*256 over [3ci][20ys][10xp] = 600 pairs (k=2: tid<88).
  int qi3[3], eb3[3];
  uint civ3 = 0;
  float jv3[6];
  uint vmask = 0;
#pragma unroll
  for (int k = 0; k < 3; ++k) {
    int p = tid + k * 256;
    int pc = p < 600 ? p : 0;
    int ci = pc / 200, rem = pc - ci * 200;
    int ys = rem / 10, xp = rem - ys * 10;
    int gyy = ybase + ys, gxx = xbase + 2 * xp;
    bool inrow = (p < 600) && gyy >= 0 && gyy < 512;
    bool v0 = inrow && gxx >= 0 && gxx < 512;
    bool v1 = inrow && (gxx + 1) >= 0 && (gxx + 1) < 512;
    int cy = gyy < 0 ? 0 : (gyy > 511 ? 511 : gyy);
    int cx = gxx < 0 ? 0 : (gxx > 510 ? 510 : gxx);
    int spc = cy * 512 + cx;
    qi3[k] = (b * 3 + ci) * 1310720 + spc;
    float2 jp = *(const float2*)(gj + (b * 3 + ci) * 262144 + spc);
    jv3[k * 2] = jp.x; jv3[k * 2 + 1] = jp.y;
    eb3[k] = ci * 440 + ys * 22 + 2 * xp;
    civ3 |= (uint)(ci * 5) << (k * 4);
    if (v0) vmask |= 1u << (2 * k);
    if (v1) vmask |= 1u << (2 * k + 1);
    if (xp > 0) vmask |= 1u << (8 + k);
  }

  const float w2v = w2p[0];

  auto issue_loads = [&](int f, float2* ivr) {
    const int fo = f * 262144;
    ivr[0] = *(const float2*)(gi + qi3[0] + fo);
    ivr[1] = *(const float2*)(gi + qi3[1] + fo);
    ivr[2] = (tid < 88) ? *(const float2*)(gi + qi3[2] + fo) : make_float2(0.f, 0.f);
  };
  auto stage_frame = [&](int f, const float2* ivr) {
    const int sb2 = (f & 3) * 1320;
#pragma unroll
    for (int k = 0; k < 3; ++k) {
      if (k == 2 && tid >= 88) break;
      float bv = blv_s[((civ3 >> (k * 4)) & 15u) + f];
      float iv0 = ivr[k].x, iv1 = ivr[k].y;
      float x0 = ((vmask >> (2 * k)) & 1u)
                   ? fmaf(w2v, (iv0 - bv) * __builtin_amdgcn_rcpf(jv3[k * 2] - bv + 1e-8f), iv0) : 0.f;
      float x1 = ((vmask >> (2 * k + 1)) & 1u)
                   ? fmaf(w2v, (iv1 - bv) * __builtin_amdgcn_rcpf(jv3[k * 2 + 1] - bv + 1e-8f), iv1) : 0.f;
      uint pk = cvt_pk_bf16(x0, x1);
      int ebb = sb2 + eb3[k];
      *(uint*)(xsh + ebb) = pk;                                     // copy0 pair (ebb even)
      if ((vmask >> (8 + k)) & 1u) xsh[ebb + 5279] = (ushort)pk;    // copy1: x0 -> idx ebb-1
      xsh[ebb + 5280] = (ushort)(pk >> 16);                         // copy1: x1 -> idx ebb
    }
  };
  auto stage_zero = [&](int slot) {
    const int sb2 = slot * 1320;
#pragma unroll
    for (int k = 0; k < 3; ++k) {
      if (k == 2 && tid >= 88) break;
      int ebb = sb2 + eb3[k];
      *(uint*)(xsh + ebb) = 0u;
      if ((vmask >> (8 + k)) & 1u) xsh[ebb + 5279] = 0;
      xsh[ebb + 5280] = 0;
    }
  };

  // ---- prologue: issue loads for frames 0,1; barrier; bl writes; stage 0,1 ----
  float2 ivr0[3], ivr1[3];
  issue_loads(0, ivr0);
  issue_loads(1, ivr1);

  __syncthreads();   // zero-init + blv_s + baseTab visible to ALL waves

#pragma unroll
  for (int c = 0; c < 3; ++c)
#pragma unroll
    for (int t = 0; t < 5; ++t)
      out[(((b * 3 + c) * 5 + t) * 512 + gy) * 512 + gx] = blv_s[c * 5 + t];

  stage_frame(0, ivr0);   // slot 0
  stage_frame(1, ivr1);   // slot 1
  __syncthreads();

  f32x4 acc2[4];
#pragma unroll
  for (int u = 0; u < 4; ++u) acc2[u] = (f32x4){0.f, 0.f, 0.f, 0.f};

#pragma unroll
  for (int tf = 0; tf < 5; ++tf) {
    // prefetch gi for frame tf+2 (consumed by stage at phase bottom; conv1+conv2 cover latency)
    float2 ivr[3];
    if (tf < 3) issue_loads(tf + 2, ivr);

    // per-tf conv1 slot bases from LDS table (2 x b128)
    int4 bE0 = *(const int4*)&baseTab[tf * 32 + kb * 8];
    int4 bE1 = *(const int4*)&baseTab[tf * 32 + kb * 8 + 4];

    // ---- conv1(tf) -> h2[tf&1] ----
    ushort* h2w = h2sh + (tf & 1) * HBUF;
    __builtin_amdgcn_s_setprio(1);
#pragma unroll
    for (int i = 0; i < 6; ++i) {
      if (i == 5 && wv != 0) continue;   // only wave 0 owns tile 20
      const int pT_ = pT[i];
      const int q = pT_ & 8191;
      f32x4 acc = bias4;
#pragma unroll
      for (int m = 0; m < 4; ++m) {
        int be0 = (m == 0) ? bE0.x : (m == 1) ? bE0.z : (m == 2) ? bE1.x : bE1.z;
        int be1 = (m == 0) ? bE0.y : (m == 1) ? bE0.w : (m == 2) ? bE1.y : bE1.w;
        const uint* p0 = (const uint*)(xsh + (be0 + q));
        const uint* p1 = (const uint*)(xsh + (be1 + q));
        union { uint4 u; bf16x8 v; } bfr;
        bfr.u = make_uint4(p0[0], p0[1], p1[0], p1[1]);
        acc = __builtin_amdgcn_mfma_f32_16x16x32_bf16(a4[m].v, bfr.v, acc, 0, 0, 0);
      }
      const bool inimg = (tmask >> (i + 8)) & 1u;
      float r0 = inimg ? leakyf(acc[0]) : 0.f;
      float r1 = inimg ? leakyf(acc[1]) : 0.f;
      float r2 = inimg ? leakyf(acc[2]) : 0.f;
      float r3 = inimg ? leakyf(acc[3]) : 0.f;
      uint p0 = cvt_pk_u32(r0, r1);
      uint p1 = cvt_pk_u32(r2, r3);
      if ((tmask >> i) & 1u)
        *(uint2*)(h2w + ((pT_ >> 13) * HCH + kb * 4)) = make_uint2(p0, p1);
    }
    __builtin_amdgcn_s_setprio(0);

    // ---- conv2(tf-1): s OUTER (one aw fragment live), u inner ----
    if (tf > 0) {
      const ushort* h2r = h2sh + ((tf - 1) & 1) * HBUF;
      const ushort* wbase = w2Ag + (tf - 1) * 5 * 64 * 8;
      __builtin_amdgcn_s_setprio(1);
#pragma unroll
      for (int s = 0; s < 5; ++s) {
        union { uint4 u; f16x8 v; } aw;
        aw.u = *(const uint4*)(wbase + (s * 64 + lane) * 8);
#pragma unroll
        for (int u = 0; u < 4; ++u) {
          const ushort* hb = h2r + (wv + u * 4) * HROW;
          union { uint4 u4; f16x8 v; } bfr;
          bfr.u4 = *(const uint4*)(hb + bOff[s]);
          acc2[u] = __builtin_amdgcn_mfma_f32_16x16x32_f16(aw.v, bfr.v, acc2[u], 0, 0, 0);
        }
      }
      __builtin_amdgcn_s_setprio(0);
    }

    // ---- stage(tf+2) -> slot (tf+2)%4 ; zero-fill slot 1 for f=5 at tf==3 ----
    if (tf < 3) stage_frame(tf + 2, ivr);
    else if (tf == 3) stage_zero(1);
    __syncthreads();
  }

  // ---- epilogue: conv2(4) from h2[0], s outer ----
  {
    const ushort* h2r = h2sh + 0 * HBUF;
    const ushort* wbase = w2Ag + 4 * 5 * 64 * 8;
#pragma unroll
    for (int s = 0; s < 5; ++s) {
      union { uint4 u; f16x8 v; } aw;
      aw.u = *(const uint4*)(wbase + (s * 64 + lane) * 8);
#pragma unroll
      for (int u = 0; u < 4; ++u) {
        const ushort* hb = h2r + (wv + u * 4) * HROW;
        union { uint4 u4; f16x8 v; } bfr;
        bfr.u4 = *(const uint4*)(hb + bOff[s]);
        acc2[u] = __builtin_amdgcn_mfma_f32_16x16x32_f16(aw.v, bfr.v, acc2[u], 0, 0, 0);
      }
    }
  }

  // ---- redistribute D[t][pos] through LDS (reuse xsh) and store t-output ----
  float* sredf = (float*)xsh;
#pragma unroll
  for (int u = 0; u < 4; ++u) {
    const int tt = wv + u * 4;
    if (kb == 0) {
#pragma unroll
      for (int r = 0; r < 4; ++r)
        sredf[r * 256 + tt * 16 + ln] = acc2[u][r];      // rows 0..3 = t 0..3
    } else if (kb == 1) {
      sredf[4 * 256 + tt * 16 + ln] = acc2[u][0];        // row 4 = t 4
    }
  }
  __syncthreads();

  const float bt2 = b_t2[0];
#pragma unroll
  for (int t = 0; t < 5; ++t) {
    float tv = 1.f / (1.f + __expf(-(sredf[t * 256 + tid] + bt2))) + t_bias[t];
    out[15728640 + ((b * 5 + t) * 512 + gy) * 512 + gx] = tv;
  }
}

extern "C" void kernel_launch(void* const* d_in, const int* in_sizes, int n_in,
                              void* d_out, int out_size, void* d_ws, size_t ws_size,
                              hipStream_t stream) {
  const float* gi = (const float*)d_in[0];
  const float* gj = (const float*)d_in[1];
  const float* w_bl1 = (const float*)d_in[2];
  const float* b_bl1 = (const float*)d_in[3];
  const float* w_bl2 = (const float*)d_in[4];
  const float* b_bl2 = (const float*)d_in[5];
  const float* w_t1 = (const float*)d_in[6];
  const float* b_t1 = (const float*)d_in[7];
  const float* w_t2 = (const float*)d_in[8];
  const float* b_t2 = (const float*)d_in[9];
  const float* w1 = (const float*)d_in[10];
  const float* w2 = (const float*)d_in[11];
  const float* t_bias = (const float*)d_in[12];
  float* out = (float*)d_out;
  char* ws = (char*)d_ws;

  uint* hist = (uint*)(ws + WS_HIST);
  double* sums = (double*)(ws + WS_DBL);
  float* blv = (float*)(ws + WS_BLV);
  ushort* wA = (ushort*)(ws + WS_WA);
  ushort* w2A = (ushort*)(ws + WS_W2A);

  hipMemsetAsync(ws, 0, WS_ZERO_BYTES, stream);

  setup_kernel<<<1, 256, 0, stream>>>(w_t1, w_t2, wA, w2A);
  stats_kernel<<<dim3(32, 72), 256, 0, stream>>>(gi, gj, sums, hist);
  finalize_kernel<<<1, 256, 0, stream>>>(hist, sums, w_bl1, b_bl1, w_bl2, b_bl2, w1, blv);
  fused_kernel<<<dim3(32, 32, 4), 256, 0, stream>>>(gi, gj, wA, b_t1, w2A, b_t2, w2, t_bias, blv, out);
}

// Round 19
// 145.714 us; speedup vs baseline: 1.0572x; 1.0572x over previous
//
#include <hip/hip_runtime.h>

typedef unsigned int uint;
typedef unsigned short ushort;
typedef short bf16x8 __attribute__((ext_vector_type(8)));
typedef _Float16 f16x8 __attribute__((ext_vector_type(8)));
typedef float f32x4 __attribute__((ext_vector_type(4)));

#define NEG_SLOPE 0.2f

// ---------------- workspace layout (bytes) ----------------
#define WS_HIST 0                       // 4*4096*4 = 65536
#define WS_DBL  65536                   // 88 doubles
#define WS_BLV  (WS_DBL + 704)         // 60 floats
#define WS_WA   (WS_BLV + 256)        // 16x128 bf16 = 4096 B
#define WS_W2A  (WS_WA + 4096)        // 5tf x 5step x 64lane x 8 f16 = 25600 B
#define WS_ZERO_BYTES (WS_DBL + 704)

// h2 LDS geometry: single buffer [18 rows][18 cols][24 ch-stride] (b128-aligned offsets)
#define HCH 24
#define HROW 432      // 18*24

__device__ __forceinline__ float leakyf(float x) { return fmaxf(x, NEG_SLOPE * x); }

__device__ __forceinline__ ushort f2bf(float f) {
  uint u = __float_as_uint(f);
  uint r = u + 0x7FFFu + ((u >> 16) & 1u);
  return (ushort)(r >> 16);
}
// pack 2 f32 -> 2 f16 in one dword (v_cvt_pkrtz_f16_f32)
__device__ __forceinline__ uint cvt_pk_u32(float a, float b) {
  union { __fp16 __attribute__((ext_vector_type(2))) h; uint u; } c;
  c.h = __builtin_amdgcn_cvt_pkrtz(a, b);
  return c.u;
}
// pack 2 f32 -> 2 bf16 in one dword (v_cvt_pk_bf16_f32, no builtin on gfx950)
__device__ __forceinline__ uint cvt_pk_bf16(float a, float b) {
  uint r;
  asm("v_cvt_pk_bf16_f32 %0, %1, %2" : "=v"(r) : "v"(a), "v"(b));
  return r;
}

// ---------------- fused stats: i-plane sums + center G/B stats + median hist + j sums ----------------
__global__ __launch_bounds__(256) void stats_kernel(const float* __restrict__ gi,
                                                    const float* __restrict__ gj,
                                                    double* __restrict__ sums,
                                                    uint* __restrict__ hist) {
  __shared__ double red[256];
  __shared__ uint lh[4096];
  const int plane = blockIdx.y;          // 0..59 = i planes, 60..71 = j planes
  const int chunk = blockIdx.x;          // 0..31
  const int tid = threadIdx.x;

  if (plane >= 60) {
    const int jp = plane - 60;
    const float4* base = (const float4*)(gj + (size_t)jp * 262144);
    double dsum = 0.0;
    for (int k = 0; k < 8; ++k) {
      float4 v = base[chunk * 2048 + k * 256 + tid];
      dsum += (double)v.x + (double)v.y + (double)v.z + (double)v.w;
    }
    red[tid] = dsum; __syncthreads();
    for (int off = 128; off > 0; off >>= 1) { if (tid < off) red[tid] += red[tid + off]; __syncthreads(); }
    if (tid == 0) atomicAdd(&sums[60 + jp], red[0]);
    return;
  }

  const int b = plane / 15;
  const int rem = plane % 15;
  const int c = rem / 5;
  const int t = rem % 5;
  const float4* base = (const float4*)(gi + (size_t)plane * 262144);
  const bool dostat = (c >= 1 && t == 2);
  const bool domed = (c == 0 && t == 2);
  if (domed) {
    for (int i = tid; i < 4096; i += 256) lh[i] = 0;
    __syncthreads();
  }
  double dsum = 0.0, dsx = 0.0, dsx2 = 0.0;
  for (int k = 0; k < 8; ++k) {
    float4 v = base[chunk * 2048 + k * 256 + tid];
    dsum += (double)v.x + (double)v.y + (double)v.z + (double)v.w;
    if (dostat || domed) {
      float arr[4] = {v.x, v.y, v.z, v.w};
#pragma unroll
      for (int q = 0; q < 4; ++q) {
        float x = fminf(fmaxf(arr[q], 0.f), 1.f) * 255.f;
        if (domed) {
          int bin = (int)(x * (4096.0f / 255.0f));
          if (bin > 4095) bin = 4095;
          atomicAdd(&lh[bin], 1u);
        } else {
          dsx += (double)x;
          dsx2 += (double)x * (double)x;
        }
      }
    }
  }
  red[tid] = dsum; __syncthreads();
  for (int off = 128; off > 0; off >>= 1) { if (tid < off) red[tid] += red[tid + off]; __syncthreads(); }
  if (tid == 0) atomicAdd(&sums[plane], red[0]);
  __syncthreads();
  if (dostat) {
    red[tid] = dsx; __syncthreads();
    for (int off = 128; off > 0; off >>= 1) { if (tid < off) red[tid] += red[tid + off]; __syncthreads(); }
    if (tid == 0) atomicAdd(&sums[72 + b * 2 + (c - 1)], red[0]);
    __syncthreads();
    red[tid] = dsx2; __syncthreads();
    for (int off = 128; off > 0; off >>= 1) { if (tid < off) red[tid] += red[tid + off]; __syncthreads(); }
    if (tid == 0) atomicAdd(&sums[80 + b * 2 + (c - 1)], red[0]);
  }
  if (domed) {
    for (int i = tid; i < 4096; i += 256) { uint v = lh[i]; if (v) atomicAdd(&hist[b * 4096 + i], v); }
  }
}

// ---------------- weight prep: bf16 conv1 A (16x128) + f16 conv2 A-table ----------------
__global__ void setup_kernel(const float* __restrict__ w_t1, const float* __restrict__ w_t2,
                             ushort* __restrict__ wA, ushort* __restrict__ w2A) {
  const int tid = threadIdx.x;
  for (int idx = tid; idx < 2048; idx += 256) {
    int o = idx >> 7, k = idx & 127, g = k >> 2, kw = k & 3;
    float v = 0.f;
    if (g < 27 && kw < 3) {
      int ci = g / 9, kd = (g % 9) / 3, kh = g % 3;
      v = w_t1[o * 81 + ci * 27 + kd * 9 + kh * 3 + kw];
    }
    wA[idx] = f2bf(v);
  }
  for (int idx = tid; idx < 12800; idx += 256) {
    int j = idx & 7;
    int lane = (idx >> 3) & 63;
    int rest = idx >> 9;            // 0..24
    int step = rest % 5;
    int tf = rest / 5;
    int ln = lane & 15, kb = lane >> 4;
    int k = kb * 8 + j;
    int tap = step * 2 + (k >> 4);
    int ch = k & 15;
    float v = 0.f;
    if (ln < 5 && tap < 9) {
      int kd = tf + 1 - ln;
      if (kd >= 0 && kd <= 2) v = w_t2[ch * 27 + kd * 9 + tap];
    }
    union { ushort s; _Float16 h; } cv; cv.h = (_Float16)v;
    w2A[idx] = cv.s;
  }
}

// ---------------- finalize: median scan + stats -> MLP -> blv ----------------
__global__ __launch_bounds__(256) void finalize_kernel(const uint* __restrict__ hist,
                                const double* __restrict__ sums,
                                const float* __restrict__ w_bl1, const float* __restrict__ b_bl1,
                                const float* __restrict__ w_bl2, const float* __restrict__ b_bl2,
                                const float* __restrict__ w1, float* __restrict__ blv) {
  __shared__ uint s[256];
  __shared__ float fv[2];
  __shared__ float rmed_s[4];
  const int tid = threadIdx.x;
  for (int b = 0; b < 4; ++b) {
    const uint* h = hist + b * 4096;
    uint loc[16]; uint part = 0;
#pragma unroll
    for (int q = 0; q < 16; ++q) { loc[q] = h[tid * 16 + q]; part += loc[q]; }
    s[tid] = part; __syncthreads();
    for (int off = 1; off < 256; off <<= 1) {
      uint v = (tid >= off) ? s[tid - off] : 0u;
      __syncthreads(); s[tid] += v; __syncthreads();
    }
    uint pref = s[tid] - part;
#pragma unroll
    for (int m = 0; m < 2; ++m) {
      uint k = 131071u + (uint)m;
      if (k >= pref && k < pref + part) {
        uint cum = pref;
        for (int q = 0; q < 16; ++q) {
          if (k < cum + loc[q]) { fv[m] = ((float)(tid * 16 + q) + 0.5f) * (255.f / 4096.f); break; }
          cum += loc[q];
        }
      }
    }
    __syncthreads();
    if (tid == 0) rmed_s[b] = 0.5f * (fv[0] + fv[1]);
    __syncthreads();
  }
  if (tid < 20) {
    const int b = tid / 5, t = tid % 5;
    const double inv = 1.0 / 262144.0;
    float bl2[3];
    bl2[0] = 140.f / (1.f + 14.4f * expf(-0.034f * rmed_s[b]));
    for (int c = 1; c < 3; ++c) {
      double m = sums[72 + b * 2 + (c - 1)] * inv;
      double ex2 = sums[80 + b * 2 + (c - 1)] * inv;
      double var = ex2 - m * m;
      if (var < 0.0) var = 0.0;
      bl2[c] = (float)(1.13 * m + 1.11 * sqrt(var) - 25.6);
    }
#pragma unroll
    for (int c = 0; c < 3; ++c)
      bl2[c] = fminf(fmaxf(bl2[c], 5.f), 250.f) * (1.f / 255.f);
    float diff[3];
    for (int c = 0; c < 3; ++c)
      diff[c] = (float)((sums[(b * 3 + c) * 5 + t] - sums[60 + b * 3 + c]) * inv);
    float h1[16];
    for (int o = 0; o < 16; ++o) {
      float sv = b_bl1[o];
      for (int c = 0; c < 3; ++c) sv += w_bl1[o * 3 + c] * diff[c];
      h1[o] = leakyf(sv);
    }
    const float w1v = w1[0];
    for (int c = 0; c < 3; ++c) {
      float sv = b_bl2[c];
      for (int o = 0; o < 16; ++o) sv += w_bl2[c * 16 + o] * h1[o];
      float sg = 1.f / (1.f + expf(-sv));
      blv[(b * 3 + c) * 5 + t] = bl2[c] + w1v * sg;
    }
  }
}

// ---------------- fused: 2 barriers/frame, single h2 buffer, ~37.4 KB LDS -> 4 blocks/CU ----------------
// Phase tf: conv1(tf)->h2; BAR; { conv2(tf) s-outer || stage(tf+2)->slot (tf+2)%3 }; BAR.
// x slots: f%3 rotation + permanent zero slot 3 (OOB/pad reads). Register-slim (s-outer conv2).
__global__ __launch_bounds__(256, 4) void fused_kernel(
    const float* __restrict__ gi, const float* __restrict__ gj,
    const ushort* __restrict__ wAg, const float* __restrict__ b_t1,
    const ushort* __restrict__ w2Ag, const float* __restrict__ b_t2,
    const float* __restrict__ w2p, const float* __restrict__ t_bias,
    const float* __restrict__ blv, float* __restrict__ out) {
  __shared__ __align__(16) ushort xsh[10560];      // 2 parity copies x 4 slots x [3][20][22] bf16
  __shared__ __align__(16) ushort h2sh[324 * HCH]; // h2 f16 single buffer [18][18][24]
  __shared__ __align__(16) int baseTab[160];       // [tf][kb][e] conv1 slot bases
  __shared__ float blv_s[15];

  const int b = blockIdx.z;
  const int lin = blockIdx.y * 32 + blockIdx.x;
  const int swz = (lin & 7) * 128 + (lin >> 3);
  const int tY = swz >> 5, tX = swz & 31;
  const int tid = threadIdx.x;
  const int wv = tid >> 6;
  const int lane = tid & 63;
  const int ln = lane & 15;
  const int kb = lane >> 4;
  const int ty = tid >> 4, tx = tid & 15;
  const int gy = tY * 16 + ty, gx = tX * 16 + tx;
  const int ybase = tY * 16 - 2, xbase = tX * 16 - 2;

  if (tid < 15) blv_s[tid] = blv[b * 15 + tid];
  for (int i = tid; i < 5280; i += 256) ((uint*)xsh)[i] = 0u;
  // baseTab[tf][kb][e]: slot = f%3 for valid f=tf+kd-1, else zero slot 3 (incl. pad groups).
  if (tid < 160) {
    int tf_ = tid >> 5, kb_ = (tid >> 3) & 3, e = tid & 7;
    int g = (e >> 1) * 8 + kb_ * 2 + (e & 1);
    int sl = 3, sb = 0;
    if (g < 27) {
      int ci = g / 9, r9 = g % 9, kd = r9 / 3, kh = r9 % 3;
      sb = ci * 440 + kh * 22;
      int f = tf_ + kd - 1;
      if (f >= 0 && f <= 4) sl = f % 3;
    }
    baseTab[tid] = sb + sl * 1320;
  }

  // conv1 A fragments + bias
  union { uint4 u; bf16x8 v; } a4[4];
#pragma unroll
  for (int m = 0; m < 4; ++m)
    a4[m].u = *(const uint4*)(wAg + ln * 128 + m * 32 + kb * 8);
  f32x4 bias4;
#pragma unroll
  for (int r = 0; r < 4; ++r) bias4[r] = b_t1[kb * 4 + r];

  // conv1 per-tile statics (tile = wv + i*4): pT = q | (pe<<13)
  int pT[6];
  uint tmask = 0;   // bit i: pos<324 (store valid); bit i+8: inimg
#pragma unroll
  for (int i = 0; i < 6; ++i) {
    int tile = wv + i * 4;
    int pos = tile * 16 + ln;
    int pe = pos < 324 ? pos : 323;
    int y0 = pe / 18, x0 = pe - y0 * 18;
    int p = x0 & 1;
    pT[i] = (y0 * 22 + x0 - p + p * 5280) | (pe << 13);
    int gyh = tY * 16 - 1 + y0, gxh = tX * 16 - 1 + x0;
    if (pos < 324) tmask |= 1u << i;
    if (gyh >= 0 && gyh < 512 && gxh >= 0 && gxh < 512) tmask |= 1u << (i + 8);
  }

  // conv2 per-lane B offsets (elem units; every term mult of 8 elems = 16 B -> b128-aligned)
  int bOff[5];
#pragma unroll
  for (int s = 0; s < 5; ++s) {
    int tap = s * 2 + (kb >> 1); if (tap > 8) tap = 8;
    int kh = tap / 3, kw = tap - kh * 3;
    bOff[s] = kh * HROW + kw * HCH + (kb & 1) * 8 + ln * HCH;
  }

  // staging precompute: PAIRS. p = tid + k*256 over [3ci][20ys][10xp] = 600 pairs (k=2: tid<88).
  int qi3[3], eb3[3];
  uint civ3 = 0;
  float jv3[6];
  uint vmask = 0;
#pragma unroll
  for (int k = 0; k < 3; ++k) {
    int p = tid + k * 256;
    int pc = p < 600 ? p : 0;
    int ci = pc / 200, rem = pc - ci * 200;
    int ys = rem / 10, xp = rem - ys * 10;
    int gyy = ybase + ys, gxx = xbase + 2 * xp;
    bool inrow = (p < 600) && gyy >= 0 && gyy < 512;
    bool v0 = inrow && gxx >= 0 && gxx < 512;
    bool v1 = inrow && (gxx + 1) >= 0 && (gxx + 1) < 512;
    int cy = gyy < 0 ? 0 : (gyy > 511 ? 511 : gyy);
    int cx = gxx < 0 ? 0 : (gxx > 510 ? 510 : gxx);
    int spc = cy * 512 + cx;
    qi3[k] = (b * 3 + ci) * 1310720 + spc;
    float2 jp = *(const float2*)(gj + (b * 3 + ci) * 262144 + spc);
    jv3[k * 2] = jp.x; jv3[k * 2 + 1] = jp.y;
    eb3[k] = ci * 440 + ys * 22 + 2 * xp;
    civ3 |= (uint)(ci * 5) << (k * 4);
    if (v0) vmask |= 1u << (2 * k);
    if (v1) vmask |= 1u << (2 * k + 1);
    if (xp > 0) vmask |= 1u << (8 + k);
  }

  const float w2v = w2p[0];

  auto issue_loads = [&](int f, float2* ivr) {
    const int fo = f * 262144;
    ivr[0] = *(const float2*)(gi + qi3[0] + fo);
    ivr[1] = *(const float2*)(gi + qi3[1] + fo);
    ivr[2] = (tid < 88) ? *(const float2*)(gi + qi3[2] + fo) : make_float2(0.f, 0.f);
  };
  auto stage_frame = [&](int f, const float2* ivr) {
    const int slot = (f >= 3) ? f - 3 : f;   // f % 3
    const int sb2 = slot * 1320;
#pragma unroll
    for (int k = 0; k < 3; ++k) {
      if (k == 2 && tid >= 88) break;
      float bv = blv_s[((civ3 >> (k * 4)) & 15u) + f];
      float iv0 = ivr[k].x, iv1 = ivr[k].y;
      float x0 = ((vmask >> (2 * k)) & 1u)
                   ? fmaf(w2v, (iv0 - bv) * __builtin_amdgcn_rcpf(jv3[k * 2] - bv + 1e-8f), iv0) : 0.f;
      float x1 = ((vmask >> (2 * k + 1)) & 1u)
                   ? fmaf(w2v, (iv1 - bv) * __builtin_amdgcn_rcpf(jv3[k * 2 + 1] - bv + 1e-8f), iv1) : 0.f;
      uint pk = cvt_pk_bf16(x0, x1);
      int ebb = sb2 + eb3[k];
      *(uint*)(xsh + ebb) = pk;                                     // copy0 pair (ebb even)
      if ((vmask >> (8 + k)) & 1u) xsh[ebb + 5279] = (ushort)pk;    // copy1: x0 -> idx ebb-1
      xsh[ebb + 5280] = (ushort)(pk >> 16);                         // copy1: x1 -> idx ebb
    }
  };

  // ---- prologue: issue loads for frames 0,1; barrier; bl writes; stage 0,1 ----
  float2 ivr0[3], ivr1[3];
  issue_loads(0, ivr0);
  issue_loads(1, ivr1);

  __syncthreads();   // zero-init + blv_s + baseTab visible to ALL waves

#pragma unroll
  for (int c = 0; c < 3; ++c)
#pragma unroll
    for (int t = 0; t < 5; ++t)
      out[(((b * 3 + c) * 5 + t) * 512 + gy) * 512 + gx] = blv_s[c * 5 + t];

  stage_frame(0, ivr0);   // slot 0
  stage_frame(1, ivr1);   // slot 1
  __syncthreads();

  f32x4 acc2[4];
#pragma unroll
  for (int u = 0; u < 4; ++u) acc2[u] = (f32x4){0.f, 0.f, 0.f, 0.f};

#pragma unroll
  for (int tf = 0; tf < 5; ++tf) {
    // prefetch gi for frame tf+2 (consumed by stage after next barrier; conv1 covers latency)
    float2 ivr[3];
    if (tf < 3) issue_loads(tf + 2, ivr);

    // per-tf conv1 slot bases from LDS table (2 x b128)
    int4 bE0 = *(const int4*)&baseTab[tf * 32 + kb * 8];
    int4 bE1 = *(const int4*)&baseTab[tf * 32 + kb * 8 + 4];

    // ---- conv1(tf) -> h2 ----
    __builtin_amdgcn_s_setprio(1);
#pragma unroll
    for (int i = 0; i < 6; ++i) {
      if (i == 5 && wv != 0) continue;   // only wave 0 owns tile 20
      const int pT_ = pT[i];
      const int q = pT_ & 8191;
      f32x4 acc = bias4;
#pragma unroll
      for (int m = 0; m < 4; ++m) {
        int be0 = (m == 0) ? bE0.x : (m == 1) ? bE0.z : (m == 2) ? bE1.x : bE1.z;
        int be1 = (m == 0) ? bE0.y : (m == 1) ? bE0.w : (m == 2) ? bE1.y : bE1.w;
        const uint* p0 = (const uint*)(xsh + (be0 + q));
        const uint* p1 = (const uint*)(xsh + (be1 + q));
        union { uint4 u; bf16x8 v; } bfr;
        bfr.u = make_uint4(p0[0], p0[1], p1[0], p1[1]);
        acc = __builtin_amdgcn_mfma_f32_16x16x32_bf16(a4[m].v, bfr.v, acc, 0, 0, 0);
      }
      const bool inimg = (tmask >> (i + 8)) & 1u;
      float r0 = inimg ? leakyf(acc[0]) : 0.f;
      float r1 = inimg ? leakyf(acc[1]) : 0.f;
      float r2 = inimg ? leakyf(acc[2]) : 0.f;
      float r3 = inimg ? leakyf(acc[3]) : 0.f;
      uint p0 = cvt_pk_u32(r0, r1);
      uint p1 = cvt_pk_u32(r2, r3);
      if ((tmask >> i) & 1u)
        *(uint2*)(h2sh + ((pT_ >> 13) * HCH + kb * 4)) = make_uint2(p0, p1);
    }
    __builtin_amdgcn_s_setprio(0);
    __syncthreads();

    // ---- conv2(tf): s OUTER (one aw fragment live), u inner; then stage(tf+2) ----
    {
      const ushort* wbase = w2Ag + tf * 5 * 64 * 8;
      __builtin_amdgcn_s_setprio(1);
#pragma unroll
      for (int s = 0; s < 5; ++s) {
        union { uint4 u; f16x8 v; } aw;
        aw.u = *(const uint4*)(wbase + (s * 64 + lane) * 8);
#pragma unroll
        for (int u = 0; u < 4; ++u) {
          const ushort* hb = h2sh + (wv + u * 4) * HROW;
          union { uint4 u4; f16x8 v; } bfr;
          bfr.u4 = *(const uint4*)(hb + bOff[s]);
          acc2[u] = __builtin_amdgcn_mfma_f32_16x16x32_f16(aw.v, bfr.v, acc2[u], 0, 0, 0);
        }
      }
      __builtin_amdgcn_s_setprio(0);
    }

    if (tf < 3) stage_frame(tf + 2, ivr);
    __syncthreads();
  }

  // ---- redistribute D[t][pos] through LDS (reuse xsh) and store t-output ----
  float* sredf = (float*)xsh;
#pragma unroll
  for (int u = 0; u < 4; ++u) {
    const int tt = wv + u * 4;
    if (kb == 0) {
#pragma unroll
      for (int r = 0; r < 4; ++r)
        sredf[r * 256 + tt * 16 + ln] = acc2[u][r];      // rows 0..3 = t 0..3
    } else if (kb == 1) {
      sredf[4 * 256 + tt * 16 + ln] = acc2[u][0];        // row 4 = t 4
    }
  }
  __syncthreads();

  const float bt2 = b_t2[0];
#pragma unroll
  for (int t = 0; t < 5; ++t) {
    float tv = 1.f / (1.f + __expf(-(sredf[t * 256 + tid] + bt2))) + t_bias[t];
    out[15728640 + ((b * 5 + t) * 512 + gy) * 512 + gx] = tv;
  }
}

extern "C" void kernel_launch(void* const* d_in, const int* in_sizes, int n_in,
                              void* d_out, int out_size, void* d_ws, size_t ws_size,
                              hipStream_t stream) {
  const float* gi = (const float*)d_in[0];
  const float* gj = (const float*)d_in[1];
  const float* w_bl1 = (const float*)d_in[2];
  const float* b_bl1 = (const float*)d_in[3];
  const float* w_bl2 = (const float*)d_in[4];
  const float* b_bl2 = (const float*)d_in[5];
  const float* w_t1 = (const float*)d_in[6];
  const float* b_t1 = (const float*)d_in[7];
  const float* w_t2 = (const float*)d_in[8];
  const float* b_t2 = (const float*)d_in[9];
  const float* w1 = (const float*)d_in[10];
  const float* w2 = (const float*)d_in[11];
  const float* t_bias = (const float*)d_in[12];
  float* out = (float*)d_out;
  char* ws = (char*)d_ws;

  uint* hist = (uint*)(ws + WS_HIST);
  double* sums = (double*)(ws + WS_DBL);
  float* blv = (float*)(ws + WS_BLV);
  ushort* wA = (ushort*)(ws + WS_WA);
  ushort* w2A = (ushort*)(ws + WS_W2A);

  hipMemsetAsync(ws, 0, WS_ZERO_BYTES, stream);

  setup_kernel<<<1, 256, 0, stream>>>(w_t1, w_t2, wA, w2A);
  stats_kernel<<<dim3(32, 72), 256, 0, stream>>>(gi, gj, sums, hist);
  finalize_kernel<<<1, 256, 0, stream>>>(hist, sums, w_bl1, b_bl1, w_bl2, b_bl2, w1, blv);
  fused_kernel<<<dim3(32, 32, 4), 256, 0, stream>>>(gi, gj, wA, b_t1, w2A, b_t2, w2, t_bias, blv, out);
}